// Round 6
// baseline (269.074 us; speedup 1.0000x reference)
//
#include <hip/hip_runtime.h>
#include <hip/hip_bf16.h>

// Problem constants
#define B_      64
#define C_      3
#define H_      224
#define W_      224
#define P_      (H_*W_)      // 50176 pixels per image
#define S_      196          // MAX_SEGMENTS
#define MAXPIX  400
#define E_      768          // EMBED
#define K_      1200         // C*MAXPIX
#define KP_     1216         // K padded to multiple of 32
#define CHUNK_  512
#define NCH_    (P_/CHUNK_)  // 98 chunks per image
#define M_      (B_*S_)      // 12544 GEMM rows
#define QPR2    104          // quads per row: 100 data (4 ranks x 3ch each) + 4 pad
#define GQ_GRID 4096

// K-permutation: feats and Wb both use k' = rank*3 + c  (dot product invariant).
// This makes the gather write 24B contiguous per 4-rank quad, and lets the
// gather read one pixel-interleaved 8B imgT entry per pixel (1 random txn
// instead of 3 planar ones).

typedef __attribute__((ext_vector_type(8))) short short8;
typedef __attribute__((ext_vector_type(4))) float f32x4;

__device__ inline unsigned short f2bf(float f) {
  union { float f; unsigned int u; } x; x.f = f;
  return (unsigned short)((x.u + 0x7fffu + ((x.u >> 16) & 1u)) >> 16);
}

// chunked XCD swizzle, nwg % 8 == 0: XCD k owns a contiguous span of nwg/8 blocks
__device__ inline int xcd_chunk(int wg, int nwg) {
  int q = nwg >> 3;
  return (wg & 7) * q + (wg >> 3);
}

// ---------------- img planar fp32 -> pixel-interleaved bf16x4 (into d_out scratch) ----------------
__global__ __launch_bounds__(256) void imgt_k(const float* __restrict__ img,
                                              ushort4* __restrict__ imgT) {
  int i = blockIdx.x * 256 + threadIdx.x;      // 0 .. B_*P_ (exact grid)
  int b = i / P_, p = i - b * P_;
  const float* ib = img + (size_t)b * C_ * P_;
  ushort4 o;
  o.x = f2bf(ib[p]);
  o.y = f2bf(ib[P_ + p]);
  o.z = f2bf(ib[2 * P_ + p]);
  o.w = 0;
  imgT[i] = o;
}

// ---------------- W fp32 -> bf16, K-permuted (k' = r*3+c) + K-padding ----------------
__global__ void wconv_k(const float* __restrict__ Wf, unsigned short* __restrict__ Wb) {
  int idx = blockIdx.x * 256 + threadIdx.x;     // 0 .. E_*KP_ (exact grid)
  int e = idx / KP_, k = idx - e * KP_;
  float v = 0.f;
  if (k < K_) {
    int r = k / 3, c = k - r * 3;
    v = Wf[e * K_ + c * MAXPIX + r];
  }
  Wb[idx] = f2bf(v);
}

// ---------------- per-chunk rank + histogram ----------------
__global__ __launch_bounds__(512) void rank_k(const int* __restrict__ seg,
                                              int* __restrict__ hist,
                                              unsigned short* __restrict__ rloc) {
  int b = blockIdx.x / NCH_, ch = blockIdx.x % NCH_;
  int tid = threadIdx.x, wave = tid >> 6, lane = tid & 63;
  int p = ch * CHUNK_ + tid;
  int s = seg[b * P_ + p];

  __shared__ int lhist[8][S_];
  for (int i = tid; i < 8 * S_; i += 512) ((int*)lhist)[i] = 0;
  __syncthreads();

  // count earlier lanes in this wave with the same segment id (stable raster rank)
  int r = 0;
  #pragma unroll 1
  for (int j = 0; j < 64; ++j) {
    int sj = __shfl(s, j);
    r += (j < lane && sj == s) ? 1 : 0;
  }
  atomicAdd(&lhist[wave][s], 1);
  __syncthreads();

  int off = 0;
  for (int w2 = 0; w2 < wave; ++w2) off += lhist[w2][s];
  rloc[b * P_ + p] = (unsigned short)(off + r);

  if (tid < S_) {
    int t = 0;
    #pragma unroll
    for (int w2 = 0; w2 < 8; ++w2) t += lhist[w2][tid];
    hist[(b * NCH_ + ch) * S_ + tid] = t;
  }
}

// ---------------- parallel exclusive prefix over chunks per (b, s) ----------------
__global__ __launch_bounds__(128) void prefix_k(int* __restrict__ hist, int* __restrict__ cnts) {
  int b = blockIdx.x / S_, s = blockIdx.x % S_;
  int t = threadIdx.x;
  __shared__ int sc[128];
  int v = (t < NCH_) ? hist[(b * NCH_ + t) * S_ + s] : 0;
  sc[t] = v;
  __syncthreads();
  #pragma unroll
  for (int off = 1; off < 128; off <<= 1) {
    int x = (t >= off) ? sc[t - off] : 0;
    __syncthreads();
    sc[t] += x;
    __syncthreads();
  }
  if (t < NCH_) hist[(b * NCH_ + t) * S_ + s] = sc[t] - v;   // exclusive
  if (t == NCH_ - 1) {
    int tot = sc[t];
    cnts[b * S_ + s] = tot < MAXPIX ? tot : MAXPIX;
  }
}

// ---------------- scatter pixel ids -> inv[b][s][rank] (uint16) ----------------
__global__ __launch_bounds__(256) void scatter_inv_k(const int* __restrict__ seg,
                                                     const int* __restrict__ starts,
                                                     const unsigned short* __restrict__ rloc,
                                                     unsigned short* __restrict__ inv) {
  int wg = xcd_chunk(blockIdx.x, B_ * (P_ / 256));   // contiguous pixel span per XCD
  int b = wg / (P_ / 256);
  int p = (wg % (P_ / 256)) * 256 + threadIdx.x;
  int s = seg[b * P_ + p];
  int rank = starts[(b * NCH_ + (p >> 9)) * S_ + s] + rloc[b * P_ + p];
  if (rank < MAXPIX)
    inv[(b * S_ + s) * MAXPIX + rank] = (unsigned short)p;
}

// ---------------- gather imgT -> feats rows (K-permuted, 1 txn/pixel) ----------------
// work unit = quad: 4 consecutive ranks, ALL 3 channels (one 8B imgT read per rank).
__global__ __launch_bounds__(256) void gather_k(const ushort4* __restrict__ imgT,
                                                const unsigned short* __restrict__ inv,
                                                const int* __restrict__ cnts,
                                                unsigned short* __restrict__ feats) {
  const int nq = M_ * QPR2;
  int blk = xcd_chunk(blockIdx.x, GQ_GRID);
  for (int q = blk * 256 + threadIdx.x; q < nq; q += GQ_GRID * 256) {
    int row = q / QPR2;
    int qi = q - row * QPR2;
    unsigned short* frow = feats + (size_t)row * KP_;
    if (qi >= 100) {                                   // K padding: 1200..1215
      *(ushort4*)&frow[K_ + ((qi - 100) << 2)] = make_ushort4(0, 0, 0, 0);
      continue;
    }
    int r4 = qi << 2;
    int cnt = cnts[row];
    int b = row / S_;
    ushort4 pq = *(const ushort4*)&inv[(size_t)row * MAXPIX + r4];
    const ushort4* it = imgT + (size_t)b * P_;
    ushort4 z = make_ushort4(0, 0, 0, 0);
    ushort4 v0 = (r4 + 0 < cnt) ? it[pq.x] : z;
    ushort4 v1 = (r4 + 1 < cnt) ? it[pq.y] : z;
    ushort4 v2 = (r4 + 2 < cnt) ? it[pq.z] : z;
    ushort4 v3 = (r4 + 3 < cnt) ? it[pq.w] : z;
    ushort4* dst = (ushort4*)&frow[r4 * 3];            // 24B contiguous, 8B aligned
    dst[0] = make_ushort4(v0.x, v0.y, v0.z, v1.x);
    dst[1] = make_ushort4(v1.y, v1.z, v2.x, v2.y);
    dst[2] = make_ushort4(v2.z, v3.x, v3.y, v3.z);
  }
}

// ---------------- bf16 MFMA GEMM: out[M][E] = feats[M][KP] * Wb[E][KP]^T + bias ----------------
__global__ __launch_bounds__(256) void gemm_k(const unsigned short* __restrict__ A,
                                              const unsigned short* __restrict__ Bw,
                                              const float* __restrict__ bias,
                                              float* __restrict__ out) {
  // bijective chunked swizzle (m204): nwg=588, q=73, r=4
  int bid;
  {
    int wg = blockIdx.x, q = 588 / 8, r = 588 % 8;
    int xcd = wg % 8, idx = wg / 8;
    bid = (xcd < r) ? xcd * (q + 1) + idx : r * (q + 1) + (xcd - r) * q + idx;
  }
  const int nb = bid % (E_ / 128);   // 0..5
  const int mb = bid / (E_ / 128);   // 0..97
  const int tid = threadIdx.x;
  const int w = tid >> 6, l = tid & 63;
  const int wr = w >> 1, wc = w & 1;

  __shared__ __align__(16) unsigned short As[128 * 32];
  __shared__ __align__(16) unsigned short Bs[128 * 32];

  f32x4 acc[4][4] = {};

  const int lrow = l >> 2;        // 0..15
  const int lcol = (l & 3) * 8;   // element offset within 32-wide K slice
  const int kk = (l >> 4) * 8;    // fragment K offset

  for (int k0 = 0; k0 < KP_; k0 += 32) {
    #pragma unroll
    for (int q = 0; q < 2; ++q) {
      int r = (w * 2 + q) * 16 + lrow;
      const unsigned short* ga = A + (size_t)(mb * 128 + r) * KP_ + k0 + lcol;
      __builtin_amdgcn_global_load_lds((const __attribute__((address_space(1))) unsigned int*)ga,
                                       (__attribute__((address_space(3))) unsigned int*)&As[(w * 2 + q) * 512],
                                       16, 0, 0);
      const unsigned short* gb = Bw + (size_t)(nb * 128 + r) * KP_ + k0 + lcol;
      __builtin_amdgcn_global_load_lds((const __attribute__((address_space(1))) unsigned int*)gb,
                                       (__attribute__((address_space(3))) unsigned int*)&Bs[(w * 2 + q) * 512],
                                       16, 0, 0);
    }
    __syncthreads();

    short8 af[4], bf[4];
    #pragma unroll
    for (int mi = 0; mi < 4; ++mi)
      af[mi] = *(const short8*)&As[(wr * 64 + mi * 16 + (l & 15)) * 32 + kk];
    #pragma unroll
    for (int ni = 0; ni < 4; ++ni)
      bf[ni] = *(const short8*)&Bs[(wc * 64 + ni * 16 + (l & 15)) * 32 + kk];
    #pragma unroll
    for (int mi = 0; mi < 4; ++mi)
      #pragma unroll
      for (int ni = 0; ni < 4; ++ni)
        acc[mi][ni] = __builtin_amdgcn_mfma_f32_16x16x32_bf16(af[mi], bf[ni], acc[mi][ni], 0, 0, 0);
    __syncthreads();
  }

  // epilogue: C/D layout col = lane&15, row = (lane>>4)*4 + reg  [verified m89/m91]
  const int r0 = (l >> 4) * 4;
  const int c0 = l & 15;
  #pragma unroll
  for (int mi = 0; mi < 4; ++mi) {
    #pragma unroll
    for (int ni = 0; ni < 4; ++ni) {
      int col = nb * 128 + wc * 64 + ni * 16 + c0;
      float bv = bias[col];
      int row = mb * 128 + wr * 64 + mi * 16 + r0;
      #pragma unroll
      for (int r = 0; r < 4; ++r)
        out[(size_t)(row + r) * E_ + col] = acc[mi][ni][r] + bv;
    }
  }
}

extern "C" void kernel_launch(void* const* d_in, const int* in_sizes, int n_in,
                              void* d_out, int out_size, void* d_ws, size_t ws_size,
                              hipStream_t stream) {
  const float* img  = (const float*)d_in[0];   // [64,3,224,224]
  const int*   seg  = (const int*)d_in[1];     // [64,224,224]
  const float* Wf   = (const float*)d_in[2];   // [768,1200]
  const float* bias = (const float*)d_in[3];   // [768]
  float* out = (float*)d_out;                  // [64,196,768]

  // workspace layout with lifetime overlap (total 42.5 MB):
  //   [Wb 1.87M][inv 10.04M][cnts 0.05M][feats 30.5M]
  //   rloc/hist overlaid inside feats (dead before gather_k writes feats).
  // imgT (25.7 MB, bf16x4 per pixel) lives in d_out — dead before gemm writes out.
  constexpr size_t WB_BYTES    = (size_t)E_ * KP_ * 2;        //  1,867,776
  constexpr size_t INV_BYTES   = (size_t)M_ * MAXPIX * 2;     // 10,035,200
  constexpr size_t CNT_BYTES   = (size_t)M_ * 4;              //     50,176
  constexpr size_t RLOC_BYTES  = (size_t)B_ * P_ * 2;         //  6,422,528
  char* ws = (char*)d_ws;
  unsigned short* Wb    = (unsigned short*)ws;
  unsigned short* inv   = (unsigned short*)(ws + WB_BYTES);
  int*            cnts  = (int*)(ws + WB_BYTES + INV_BYTES);
  unsigned short* feats = (unsigned short*)(ws + WB_BYTES + INV_BYTES + CNT_BYTES);
  unsigned short* rloc  = feats;                                      // overlaid
  int*            hist  = (int*)((char*)feats + RLOC_BYTES);          // overlaid
  ushort4*        imgT  = (ushort4*)d_out;                            // scratch in out

  imgt_k<<<(B_ * P_) / 256, 256, 0, stream>>>(img, imgT);
  wconv_k<<<(E_ * KP_) / 256, 256, 0, stream>>>(Wf, Wb);
  rank_k<<<B_ * NCH_, 512, 0, stream>>>(seg, hist, rloc);
  prefix_k<<<B_ * S_, 128, 0, stream>>>(hist, cnts);
  scatter_inv_k<<<B_ * (P_ / 256), 256, 0, stream>>>(seg, hist, rloc, inv);
  gather_k<<<GQ_GRID, 256, 0, stream>>>(imgT, inv, cnts, feats);
  gemm_k<<<(M_ / 128) * (E_ / 128), 256, 0, stream>>>(feats, Wb, bias, out);
}

// Round 8
// 238.278 us; speedup vs baseline: 1.1292x; 1.1292x over previous
//
#include <hip/hip_runtime.h>
#include <hip/hip_bf16.h>

// Problem constants
#define B_      64
#define C_      3
#define H_      224
#define W_      224
#define P_      (H_*W_)      // 50176 pixels per image
#define S_      196          // MAX_SEGMENTS
#define MAXPIX  400
#define E_      768          // EMBED
#define K_      1200         // C*MAXPIX
#define KP_     1216         // K padded to multiple of 32
#define CHUNK_  512
#define NCH_    (P_/CHUNK_)  // 98 chunks per image
#define M_      (B_*S_)      // 12544 GEMM rows

// K-permutation: feats and Wb both use k' = rank*3 + c (dot product invariant).
// One pixel's 3 bf16 channels are 6 CONTIGUOUS bytes in its feats row -> the
// value-scatter is 2 aligned store txns per pixel (dword+short, parity split).

typedef __attribute__((ext_vector_type(8))) short short8;
typedef __attribute__((ext_vector_type(4))) float f32x4;

__device__ inline unsigned short f2bf(float f) {
  union { float f; unsigned int u; } x; x.f = f;
  return (unsigned short)((x.u + 0x7fffu + ((x.u >> 16) & 1u)) >> 16);
}

// chunked XCD swizzle, nwg % 8 == 0: XCD k owns a contiguous span of nwg/8 blocks
__device__ inline int xcd_chunk(int wg, int nwg) {
  int q = nwg >> 3;
  return (wg & 7) * q + (wg >> 3);
}

// ---------------- zero feats ----------------
__global__ void zero_k(int4* __restrict__ p, int n4) {
  int i = blockIdx.x * blockDim.x + threadIdx.x;
  int stride = gridDim.x * blockDim.x;
  int4 z = make_int4(0, 0, 0, 0);
  for (; i < n4; i += stride) p[i] = z;
}

// ---------------- W fp32 -> bf16, K-permuted (k' = r*3+c) + K-padding ----------------
__global__ void wconv_k(const float* __restrict__ Wf, unsigned short* __restrict__ Wb) {
  int idx = blockIdx.x * 256 + threadIdx.x;     // 0 .. E_*KP_ (exact grid)
  int e = idx / KP_, k = idx - e * KP_;
  float v = 0.f;
  if (k < K_) {
    int r = k / 3, c = k - r * 3;
    v = Wf[e * K_ + c * MAXPIX + r];
  }
  Wb[idx] = f2bf(v);
}

// ---------------- per-chunk rank + histogram ----------------
__global__ __launch_bounds__(512) void rank_k(const int* __restrict__ seg,
                                              int* __restrict__ hist,
                                              unsigned short* __restrict__ rloc) {
  int b = blockIdx.x / NCH_, ch = blockIdx.x % NCH_;
  int tid = threadIdx.x, wave = tid >> 6, lane = tid & 63;
  int p = ch * CHUNK_ + tid;
  int s = seg[b * P_ + p];

  __shared__ int lhist[8][S_];
  for (int i = tid; i < 8 * S_; i += 512) ((int*)lhist)[i] = 0;
  __syncthreads();

  // count earlier lanes in this wave with the same segment id (stable raster rank)
  int r = 0;
  #pragma unroll 1
  for (int j = 0; j < 64; ++j) {
    int sj = __shfl(s, j);
    r += (j < lane && sj == s) ? 1 : 0;
  }
  atomicAdd(&lhist[wave][s], 1);
  __syncthreads();

  int off = 0;
  for (int w2 = 0; w2 < wave; ++w2) off += lhist[w2][s];
  rloc[b * P_ + p] = (unsigned short)(off + r);

  if (tid < S_) {
    int t = 0;
    #pragma unroll
    for (int w2 = 0; w2 < 8; ++w2) t += lhist[w2][tid];
    hist[(b * NCH_ + ch) * S_ + tid] = t;
  }
}

// ---------------- parallel exclusive prefix over chunks per (b, s) ----------------
__global__ __launch_bounds__(128) void prefix_k(int* __restrict__ hist) {
  int b = blockIdx.x / S_, s = blockIdx.x % S_;
  int t = threadIdx.x;
  __shared__ int sc[128];
  int v = (t < NCH_) ? hist[(b * NCH_ + t) * S_ + s] : 0;
  sc[t] = v;
  __syncthreads();
  #pragma unroll
  for (int off = 1; off < 128; off <<= 1) {
    int x = (t >= off) ? sc[t - off] : 0;
    __syncthreads();
    sc[t] += x;
    __syncthreads();
  }
  if (t < NCH_) hist[(b * NCH_ + t) * S_ + s] = sc[t] - v;   // exclusive
}

// ---------------- scatter pixel VALUES -> feats (fire-and-forget stores) ----------------
// Per pixel: 3 coalesced planar img reads, one 6B contiguous store (as aligned
// dword+short, parity-split). XCD-chunked pixel spans => each XCD's feats
// target window is ~3.8MB and L2-resident; dirty lines aggregate locally.
__global__ __launch_bounds__(256) void scatter_vals_k(const float* __restrict__ img,
                                                      const int* __restrict__ seg,
                                                      const int* __restrict__ starts,
                                                      const unsigned short* __restrict__ rloc,
                                                      unsigned short* __restrict__ feats) {
  int wg = xcd_chunk(blockIdx.x, B_ * (P_ / 256));   // contiguous pixel span per XCD
  int b = wg / (P_ / 256);
  int p = (wg % (P_ / 256)) * 256 + threadIdx.x;
  int s = seg[b * P_ + p];
  int rank = starts[(b * NCH_ + (p >> 9)) * S_ + s] + rloc[b * P_ + p];
  if (rank < MAXPIX) {
    const float* ib = img + (size_t)b * C_ * P_;
    unsigned short c0 = f2bf(ib[p]);
    unsigned short c1 = f2bf(ib[P_ + p]);
    unsigned short c2 = f2bf(ib[2 * P_ + p]);
    char* bp = (char*)(feats + (size_t)(b * S_ + s) * KP_) + 6 * (size_t)rank;
    if (rank & 1) {
      *(unsigned short*)bp = c0;
      *(unsigned int*)(bp + 2) = (unsigned int)c1 | ((unsigned int)c2 << 16);
    } else {
      *(unsigned int*)bp = (unsigned int)c0 | ((unsigned int)c1 << 16);
      *(unsigned short*)(bp + 4) = c2;
    }
  }
}

// ---------------- bf16 MFMA GEMM: out[M][E] = feats[M][KP] * Wb[E][KP]^T + bias ----------------
__global__ __launch_bounds__(256) void gemm_k(const unsigned short* __restrict__ A,
                                              const unsigned short* __restrict__ Bw,
                                              const float* __restrict__ bias,
                                              float* __restrict__ out) {
  // bijective chunked swizzle (m204): nwg=588, q=73, r=4
  int bid;
  {
    int wg = blockIdx.x, q = 588 / 8, r = 588 % 8;
    int xcd = wg % 8, idx = wg / 8;
    bid = (xcd < r) ? xcd * (q + 1) + idx : r * (q + 1) + (xcd - r) * q + idx;
  }
  const int nb = bid % (E_ / 128);   // 0..5
  const int mb = bid / (E_ / 128);   // 0..97
  const int tid = threadIdx.x;
  const int w = tid >> 6, l = tid & 63;
  const int wr = w >> 1, wc = w & 1;

  __shared__ __align__(16) unsigned short As[128 * 32];
  __shared__ __align__(16) unsigned short Bs[128 * 32];

  f32x4 acc[4][4] = {};

  const int lrow = l >> 2;        // 0..15
  const int lcol = (l & 3) * 8;   // element offset within 32-wide K slice
  const int kk = (l >> 4) * 8;    // fragment K offset

  for (int k0 = 0; k0 < KP_; k0 += 32) {
    #pragma unroll
    for (int q = 0; q < 2; ++q) {
      int r = (w * 2 + q) * 16 + lrow;
      const unsigned short* ga = A + (size_t)(mb * 128 + r) * KP_ + k0 + lcol;
      __builtin_amdgcn_global_load_lds((const __attribute__((address_space(1))) unsigned int*)ga,
                                       (__attribute__((address_space(3))) unsigned int*)&As[(w * 2 + q) * 512],
                                       16, 0, 0);
      const unsigned short* gb = Bw + (size_t)(nb * 128 + r) * KP_ + k0 + lcol;
      __builtin_amdgcn_global_load_lds((const __attribute__((address_space(1))) unsigned int*)gb,
                                       (__attribute__((address_space(3))) unsigned int*)&Bs[(w * 2 + q) * 512],
                                       16, 0, 0);
    }
    __syncthreads();

    short8 af[4], bf[4];
    #pragma unroll
    for (int mi = 0; mi < 4; ++mi)
      af[mi] = *(const short8*)&As[(wr * 64 + mi * 16 + (l & 15)) * 32 + kk];
    #pragma unroll
    for (int ni = 0; ni < 4; ++ni)
      bf[ni] = *(const short8*)&Bs[(wc * 64 + ni * 16 + (l & 15)) * 32 + kk];
    #pragma unroll
    for (int mi = 0; mi < 4; ++mi)
      #pragma unroll
      for (int ni = 0; ni < 4; ++ni)
        acc[mi][ni] = __builtin_amdgcn_mfma_f32_16x16x32_bf16(af[mi], bf[ni], acc[mi][ni], 0, 0, 0);
    __syncthreads();
  }

  // epilogue: C/D layout col = lane&15, row = (lane>>4)*4 + reg  [verified m89/m91]
  const int r0 = (l >> 4) * 4;
  const int c0 = l & 15;
  #pragma unroll
  for (int mi = 0; mi < 4; ++mi) {
    #pragma unroll
    for (int ni = 0; ni < 4; ++ni) {
      int col = nb * 128 + wc * 64 + ni * 16 + c0;
      float bv = bias[col];
      int row = mb * 128 + wr * 64 + mi * 16 + r0;
      #pragma unroll
      for (int r = 0; r < 4; ++r)
        out[(size_t)(row + r) * E_ + col] = acc[mi][ni][r] + bv;
    }
  }
}

extern "C" void kernel_launch(void* const* d_in, const int* in_sizes, int n_in,
                              void* d_out, int out_size, void* d_ws, size_t ws_size,
                              hipStream_t stream) {
  const float* img  = (const float*)d_in[0];   // [64,3,224,224]
  const int*   seg  = (const int*)d_in[1];     // [64,224,224]
  const float* Wf   = (const float*)d_in[2];   // [768,1200]
  const float* bias = (const float*)d_in[3];   // [768]
  float* out = (float*)d_out;                  // [64,196,768]

  // workspace layout (no overlays; total 43.7 MB — same footprint as r1-r3):
  //   [Wb 1.87M][feats 30.5M][rloc 6.42M][hist 4.92M]
  constexpr size_t WB_BYTES    = (size_t)E_ * KP_ * 2;        //  1,867,776
  constexpr size_t FEATS_BYTES = (size_t)M_ * KP_ * 2;        // 30,507,008
  constexpr size_t RLOC_BYTES  = (size_t)B_ * P_ * 2;         //  6,422,528
  char* ws = (char*)d_ws;
  unsigned short* Wb    = (unsigned short*)ws;
  unsigned short* feats = (unsigned short*)(ws + WB_BYTES);
  unsigned short* rloc  = (unsigned short*)(ws + WB_BYTES + FEATS_BYTES);
  int*            hist  = (int*)(ws + WB_BYTES + FEATS_BYTES + RLOC_BYTES);

  zero_k<<<2048, 256, 0, stream>>>((int4*)feats, (int)(FEATS_BYTES / 16));
  wconv_k<<<(E_ * KP_) / 256, 256, 0, stream>>>(Wf, Wb);
  rank_k<<<B_ * NCH_, 512, 0, stream>>>(seg, hist, rloc);
  prefix_k<<<B_ * S_, 128, 0, stream>>>(hist);
  scatter_vals_k<<<B_ * (P_ / 256), 256, 0, stream>>>(img, seg, hist, rloc, feats);
  gemm_k<<<(M_ / 128) * (E_ / 128), 256, 0, stream>>>(feats, Wb, bias, out);
}

// Round 11
// 229.899 us; speedup vs baseline: 1.1704x; 1.0364x over previous
//
#include <hip/hip_runtime.h>
#include <hip/hip_bf16.h>

// Problem constants
#define B_      64
#define C_      3
#define H_      224
#define W_      224
#define P_      (H_*W_)      // 50176 pixels per image
#define S_      196          // MAX_SEGMENTS
#define MAXPIX  400
#define E_      768          // EMBED
#define K_      1200         // C*MAXPIX
#define KP_     1216         // K padded to multiple of 32
#define CHUNK_  512
#define NCH_    (P_/CHUNK_)  // 98 chunks per image
#define M_      (B_*S_)      // 12544 GEMM rows

#define RANK_BLOCKS  (B_*NCH_)        // 6272
#define WCONV_BLOCKS ((E_*KP_)/512)   // 1824  (exact)
#define PREFIX_BLOCKS (B_*S_)         // 12544 (%8==0)
#define ZERO_BLOCKS  2048
#define FEATS_BYTES_ ((size_t)M_ * KP_ * 2)   // 30,507,008 (%128==0)

// K-permutation: feats and Wb both use k' = rank*3 + c (dot product invariant).
// One pixel's 3 bf16 channels are 6 CONTIGUOUS bytes in its feats row -> the
// value-scatter is 2 aligned store txns per pixel (dword+short, parity split).

typedef __attribute__((ext_vector_type(8))) short short8;
typedef __attribute__((ext_vector_type(4))) float f32x4;

__device__ inline unsigned short f2bf(float f) {
  union { float f; unsigned int u; } x; x.f = f;
  return (unsigned short)((x.u + 0x7fffu + ((x.u >> 16) & 1u)) >> 16);
}

// chunked XCD swizzle, nwg % 8 == 0: XCD k owns a contiguous span of nwg/8 blocks
__device__ inline int xcd_chunk(int wg, int nwg) {
  int q = nwg >> 3;
  return (wg & 7) * q + (wg >> 3);
}

// ---------------- prep: rank+hist (blocks 0..6271) | wconv (blocks 6272..8095) ----------------
__global__ __launch_bounds__(512) void prep_k(const float* __restrict__ Wf,
                                              unsigned short* __restrict__ Wb,
                                              const int* __restrict__ seg,
                                              int* __restrict__ hist,
                                              unsigned short* __restrict__ rloc) {
  int blk = blockIdx.x;
  if (blk >= RANK_BLOCKS) {
    // ---- wconv: W fp32 -> bf16, K-permuted (k'=r*3+c), K-padded; 512 elems/block
    int idx = (blk - RANK_BLOCKS) * 512 + threadIdx.x;   // 0 .. E_*KP_ (exact)
    int e = idx / KP_, k = idx - e * KP_;
    float v = 0.f;
    if (k < K_) {
      int r = k / 3, c = k - r * 3;
      v = Wf[e * K_ + c * MAXPIX + r];
    }
    Wb[idx] = f2bf(v);
    return;
  }
  // ---- rank: per-chunk stable raster rank + per-chunk histogram
  int b = blk / NCH_, ch = blk % NCH_;
  int tid = threadIdx.x, wave = tid >> 6, lane = tid & 63;
  int p = ch * CHUNK_ + tid;
  int s = seg[b * P_ + p];

  __shared__ int lhist[8][S_];
  for (int i = tid; i < 8 * S_; i += 512) ((int*)lhist)[i] = 0;
  __syncthreads();

  int r = 0;
  #pragma unroll 1
  for (int j = 0; j < 64; ++j) {
    int sj = __shfl(s, j);
    r += (j < lane && sj == s) ? 1 : 0;
  }
  atomicAdd(&lhist[wave][s], 1);
  __syncthreads();

  int off = 0;
  for (int w2 = 0; w2 < wave; ++w2) off += lhist[w2][s];
  rloc[b * P_ + p] = (unsigned short)(off + r);

  if (tid < S_) {
    int t = 0;
    #pragma unroll
    for (int w2 = 0; w2 < 8; ++w2) t += lhist[w2][tid];
    hist[(b * NCH_ + ch) * S_ + tid] = t;
  }
}

// ---------------- prefix (blocks 0..12543) | XCD-affine feats zero (12544..14591) ----------------
// Zero sub-block j lands on XCD j%8 (12544%8==0) and zeroes exactly the feats
// window that XCD j%8's scatter blocks will store into (images 8*(j%8)..8*(j%8)+7)
// -> zeroed-dirty lines are resident in the RIGHT L2 when scatter runs.
__global__ __launch_bounds__(128) void prefix_zero_k(int* __restrict__ hist,
                                                     int4* __restrict__ feats4) {
  int blk = blockIdx.x;
  if (blk >= PREFIX_BLOCKS) {
    int j = blk - PREFIX_BLOCKS;
    int r = j & 7;                                   // target XCD / feats region
    const int REG4 = (int)(FEATS_BYTES_ / 8 / 16);   // 238336 int4 per region
    int4* base = feats4 + (size_t)r * REG4;
    int4 z = make_int4(0, 0, 0, 0);
    for (int i = (j >> 3) * 128 + threadIdx.x; i < REG4; i += (ZERO_BLOCKS / 8) * 128)
      base[i] = z;
    return;
  }
  int b = blk / S_, s = blk % S_;
  int t = threadIdx.x;
  __shared__ int sc[128];
  int v = (t < NCH_) ? hist[(b * NCH_ + t) * S_ + s] : 0;
  sc[t] = v;
  __syncthreads();
  #pragma unroll
  for (int off = 1; off < 128; off <<= 1) {
    int x = (t >= off) ? sc[t - off] : 0;
    __syncthreads();
    sc[t] += x;
    __syncthreads();
  }
  if (t < NCH_) hist[(b * NCH_ + t) * S_ + s] = sc[t] - v;   // exclusive
}

// ---------------- scatter pixel VALUES -> feats (fire-and-forget stores) ----------------
__global__ __launch_bounds__(256) void scatter_vals_k(const float* __restrict__ img,
                                                      const int* __restrict__ seg,
                                                      const int* __restrict__ starts,
                                                      const unsigned short* __restrict__ rloc,
                                                      unsigned short* __restrict__ feats) {
  int wg = xcd_chunk(blockIdx.x, B_ * (P_ / 256));   // contiguous pixel span per XCD
  int b = wg / (P_ / 256);
  int p = (wg % (P_ / 256)) * 256 + threadIdx.x;
  int s = seg[b * P_ + p];
  int rank = starts[(b * NCH_ + (p >> 9)) * S_ + s] + rloc[b * P_ + p];
  if (rank < MAXPIX) {
    const float* ib = img + (size_t)b * C_ * P_;
    unsigned short c0 = f2bf(ib[p]);
    unsigned short c1 = f2bf(ib[P_ + p]);
    unsigned short c2 = f2bf(ib[2 * P_ + p]);
    char* bp = (char*)(feats + (size_t)(b * S_ + s) * KP_) + 6 * (size_t)rank;
    if (rank & 1) {
      *(unsigned short*)bp = c0;
      *(unsigned int*)(bp + 2) = (unsigned int)c1 | ((unsigned int)c2 << 16);
    } else {
      *(unsigned int*)bp = (unsigned int)c0 | ((unsigned int)c1 << 16);
      *(unsigned short*)(bp + 4) = c2;
    }
  }
}

// ---------------- bf16 MFMA GEMM: out[M][E] = feats[M][KP] * Wb[E][KP]^T + bias ----------------
__global__ __launch_bounds__(256) void gemm_k(const unsigned short* __restrict__ A,
                                              const unsigned short* __restrict__ Bw,
                                              const float* __restrict__ bias,
                                              float* __restrict__ out) {
  // bijective chunked swizzle (m204): nwg=588, q=73, r=4
  int bid;
  {
    int wg = blockIdx.x, q = 588 / 8, r = 588 % 8;
    int xcd = wg % 8, idx = wg / 8;
    bid = (xcd < r) ? xcd * (q + 1) + idx : r * (q + 1) + (xcd - r) * q + idx;
  }
  const int nb = bid % (E_ / 128);   // 0..5
  const int mb = bid / (E_ / 128);   // 0..97
  const int tid = threadIdx.x;
  const int w = tid >> 6, l = tid & 63;
  const int wr = w >> 1, wc = w & 1;

  __shared__ __align__(16) unsigned short As[128 * 32];
  __shared__ __align__(16) unsigned short Bs[128 * 32];

  f32x4 acc[4][4] = {};

  const int lrow = l >> 2;        // 0..15
  const int lcol = (l & 3) * 8;   // element offset within 32-wide K slice
  const int kk = (l >> 4) * 8;    // fragment K offset

  for (int k0 = 0; k0 < KP_; k0 += 32) {
    #pragma unroll
    for (int q = 0; q < 2; ++q) {
      int r = (w * 2 + q) * 16 + lrow;
      const unsigned short* ga = A + (size_t)(mb * 128 + r) * KP_ + k0 + lcol;
      __builtin_amdgcn_global_load_lds((const __attribute__((address_space(1))) unsigned int*)ga,
                                       (__attribute__((address_space(3))) unsigned int*)&As[(w * 2 + q) * 512],
                                       16, 0, 0);
      const unsigned short* gb = Bw + (size_t)(nb * 128 + r) * KP_ + k0 + lcol;
      __builtin_amdgcn_global_load_lds((const __attribute__((address_space(1))) unsigned int*)gb,
                                       (__attribute__((address_space(3))) unsigned int*)&Bs[(w * 2 + q) * 512],
                                       16, 0, 0);
    }
    __syncthreads();

    short8 af[4], bf[4];
    #pragma unroll
    for (int mi = 0; mi < 4; ++mi)
      af[mi] = *(const short8*)&As[(wr * 64 + mi * 16 + (l & 15)) * 32 + kk];
    #pragma unroll
    for (int ni = 0; ni < 4; ++ni)
      bf[ni] = *(const short8*)&Bs[(wc * 64 + ni * 16 + (l & 15)) * 32 + kk];
    #pragma unroll
    for (int mi = 0; mi < 4; ++mi)
      #pragma unroll
      for (int ni = 0; ni < 4; ++ni)
        acc[mi][ni] = __builtin_amdgcn_mfma_f32_16x16x32_bf16(af[mi], bf[ni], acc[mi][ni], 0, 0, 0);
    __syncthreads();
  }

  // epilogue: C/D layout col = lane&15, row = (lane>>4)*4 + reg  [verified m89/m91]
  const int r0 = (l >> 4) * 4;
  const int c0 = l & 15;
  #pragma unroll
  for (int mi = 0; mi < 4; ++mi) {
    #pragma unroll
    for (int ni = 0; ni < 4; ++ni) {
      int col = nb * 128 + wc * 64 + ni * 16 + c0;
      float bv = bias[col];
      int row = mb * 128 + wr * 64 + mi * 16 + r0;
      #pragma unroll
      for (int r = 0; r < 4; ++r)
        out[(size_t)(row + r) * E_ + col] = acc[mi][ni][r] + bv;
    }
  }
}

extern "C" void kernel_launch(void* const* d_in, const int* in_sizes, int n_in,
                              void* d_out, int out_size, void* d_ws, size_t ws_size,
                              hipStream_t stream) {
  const float* img  = (const float*)d_in[0];   // [64,3,224,224]
  const int*   seg  = (const int*)d_in[1];     // [64,224,224]
  const float* Wf   = (const float*)d_in[2];   // [768,1200]
  const float* bias = (const float*)d_in[3];   // [768]
  float* out = (float*)d_out;                  // [64,196,768]

  // workspace layout (total 43.7 MB): [Wb 1.87M][feats 30.5M][rloc 6.42M][hist 4.92M]
  constexpr size_t WB_BYTES    = (size_t)E_ * KP_ * 2;        //  1,867,776
  constexpr size_t RLOC_BYTES  = (size_t)B_ * P_ * 2;         //  6,422,528
  char* ws = (char*)d_ws;
  unsigned short* Wb    = (unsigned short*)ws;
  unsigned short* feats = (unsigned short*)(ws + WB_BYTES);
  unsigned short* rloc  = (unsigned short*)(ws + WB_BYTES + FEATS_BYTES_);
  int*            hist  = (int*)(ws + WB_BYTES + FEATS_BYTES_ + RLOC_BYTES);

  prep_k<<<RANK_BLOCKS + WCONV_BLOCKS, 512, 0, stream>>>(Wf, Wb, seg, hist, rloc);
  prefix_zero_k<<<PREFIX_BLOCKS + ZERO_BLOCKS, 128, 0, stream>>>(hist, (int4*)feats);
  scatter_vals_k<<<B_ * (P_ / 256), 256, 0, stream>>>(img, seg, hist, rloc, feats);
  gemm_k<<<(M_ / 128) * (E_ / 128), 256, 0, stream>>>(feats, Wb, bias, out);
}

// Round 12
// 222.356 us; speedup vs baseline: 1.2101x; 1.0339x over previous
//
#include <hip/hip_runtime.h>
#include <hip/hip_bf16.h>

// Problem constants
#define B_      64
#define C_      3
#define H_      224
#define W_      224
#define P_      (H_*W_)      // 50176 pixels per image
#define S_      196          // MAX_SEGMENTS
#define MAXPIX  400
#define E_      768          // EMBED
#define K_      1200         // C*MAXPIX (logical)
#define KP2_    1600         // padded K: 4 slots per rank (c0,c1,c2,0) -> 8B/rank
#define CHUNK_  512
#define NCH_    (P_/CHUNK_)  // 98 chunks per image
#define M_      (B_*S_)      // 12544 GEMM rows

#define RANK_BLOCKS  (B_*NCH_)         // 6272
#define WCONV_BLOCKS ((E_*KP2_)/512)   // 2400 (exact)
#define PREFIX_BLOCKS (B_*S_)          // 12544
#define SCAT_BLOCKS  (B_*(P_/256))     // 12544
#define TAIL_BLOCKS  (M_/16)           // 784 (16 rows per block)

// K-permutation: feats and Wb both use k' = rank*4 + c (c=3 slot is zero in
// BOTH feats and W -> dot product invariant). One pixel's channels are ONE
// aligned 8B store (1 txn/pixel, vs 2 for the 6B layout) — A/B test of the
// "scatter is store-txn-bound" hypothesis.

typedef __attribute__((ext_vector_type(8))) short short8;
typedef __attribute__((ext_vector_type(4))) float f32x4;

__device__ inline unsigned short f2bf(float f) {
  union { float f; unsigned int u; } x; x.f = f;
  return (unsigned short)((x.u + 0x7fffu + ((x.u >> 16) & 1u)) >> 16);
}

// chunked XCD swizzle, nwg % 8 == 0: XCD k owns a contiguous span of nwg/8 blocks
__device__ inline int xcd_chunk(int wg, int nwg) {
  int q = nwg >> 3;
  return (wg & 7) * q + (wg >> 3);
}

// ---------------- prep: rank+hist (blocks 0..6271) | wconv (6272..8671) ----------------
__global__ __launch_bounds__(512) void prep_k(const float* __restrict__ Wf,
                                              unsigned short* __restrict__ Wb,
                                              const int* __restrict__ seg,
                                              int* __restrict__ hist,
                                              unsigned short* __restrict__ rloc) {
  int blk = blockIdx.x;
  if (blk >= RANK_BLOCKS) {
    // ---- wconv: W fp32 -> bf16, K-permuted (k'=4r+c, c3=0); 512 elems/block
    int idx = (blk - RANK_BLOCKS) * 512 + threadIdx.x;   // 0 .. E_*KP2_ (exact)
    int e = idx / KP2_, k = idx - e * KP2_;
    int r = k >> 2, c = k & 3;
    float v = (c < 3) ? Wf[e * K_ + c * MAXPIX + r] : 0.f;
    Wb[idx] = f2bf(v);
    return;
  }
  // ---- rank: per-chunk stable raster rank + per-chunk histogram
  int b = blk / NCH_, ch = blk % NCH_;
  int tid = threadIdx.x, wave = tid >> 6, lane = tid & 63;
  int p = ch * CHUNK_ + tid;
  int s = seg[b * P_ + p];

  __shared__ int lhist[8][S_];
  for (int i = tid; i < 8 * S_; i += 512) ((int*)lhist)[i] = 0;
  __syncthreads();

  int r = 0;
  #pragma unroll 1
  for (int j = 0; j < 64; ++j) {
    int sj = __shfl(s, j);
    r += (j < lane && sj == s) ? 1 : 0;
  }
  atomicAdd(&lhist[wave][s], 1);
  __syncthreads();

  int off = 0;
  for (int w2 = 0; w2 < wave; ++w2) off += lhist[w2][s];
  rloc[b * P_ + p] = (unsigned short)(off + r);

  if (tid < S_) {
    int t = 0;
    #pragma unroll
    for (int w2 = 0; w2 < 8; ++w2) t += lhist[w2][tid];
    hist[(b * NCH_ + ch) * S_ + tid] = t;
  }
}

// ---------------- parallel exclusive prefix over chunks per (b, s) + cnts ----------------
__global__ __launch_bounds__(128) void prefix_k(int* __restrict__ hist, int* __restrict__ cnts) {
  int b = blockIdx.x / S_, s = blockIdx.x % S_;
  int t = threadIdx.x;
  __shared__ int sc[128];
  int v = (t < NCH_) ? hist[(b * NCH_ + t) * S_ + s] : 0;
  sc[t] = v;
  __syncthreads();
  #pragma unroll
  for (int off = 1; off < 128; off <<= 1) {
    int x = (t >= off) ? sc[t - off] : 0;
    __syncthreads();
    sc[t] += x;
    __syncthreads();
  }
  if (t < NCH_) hist[(b * NCH_ + t) * S_ + s] = sc[t] - v;   // exclusive
  if (t == NCH_ - 1) {
    int tot = sc[t];
    cnts[b * S_ + s] = tot < MAXPIX ? tot : MAXPIX;
  }
}

// ---------------- scatter values (blocks 0..12543) | tail-zero (12544..13327) ----------------
// Pixel blocks: ONE aligned 8B store per pixel into feats[row][rank*4 .. +3].
// Tail blocks: zero rank slots [cnt, 400) per row (interior is densely
// overwritten by pixel stores -> no full-buffer pre-zero needed).
__global__ __launch_bounds__(256) void scatter_tail_k(const float* __restrict__ img,
                                                      const int* __restrict__ seg,
                                                      const int* __restrict__ starts,
                                                      const unsigned short* __restrict__ rloc,
                                                      const int* __restrict__ cnts,
                                                      unsigned short* __restrict__ feats) {
  int wg = xcd_chunk(blockIdx.x, SCAT_BLOCKS + TAIL_BLOCKS);
  if (wg >= SCAT_BLOCKS) {
    // ---- tail zero: 16 rows per block, 16 threads per row
    int t0 = wg - SCAT_BLOCKS;
    int row = t0 * 16 + (threadIdx.x >> 4);
    int l16 = threadIdx.x & 15;
    int cnt = cnts[row];
    unsigned short* frow = feats + (size_t)row * KP2_;
    ushort4 z = make_ushort4(0, 0, 0, 0);
    for (int r = cnt + l16; r < MAXPIX; r += 16)
      *(ushort4*)&frow[r * 4] = z;
    return;
  }
  int b = wg / (P_ / 256);
  int p = (wg % (P_ / 256)) * 256 + threadIdx.x;
  int s = seg[b * P_ + p];
  int rank = starts[(b * NCH_ + (p >> 9)) * S_ + s] + rloc[b * P_ + p];
  if (rank < MAXPIX) {
    const float* ib = img + (size_t)b * C_ * P_;
    ushort4 o;
    o.x = f2bf(ib[p]);
    o.y = f2bf(ib[P_ + p]);
    o.z = f2bf(ib[2 * P_ + p]);
    o.w = 0;
    *(ushort4*)&feats[(size_t)(b * S_ + s) * KP2_ + rank * 4] = o;
  }
}

// ---------------- bf16 MFMA GEMM: out[M][E] = feats[M][KP2] * Wb[E][KP2]^T + bias ----------------
__global__ __launch_bounds__(256) void gemm_k(const unsigned short* __restrict__ A,
                                              const unsigned short* __restrict__ Bw,
                                              const float* __restrict__ bias,
                                              float* __restrict__ out) {
  // bijective chunked swizzle (m204): nwg=588, q=73, r=4
  int bid;
  {
    int wg = blockIdx.x, q = 588 / 8, r = 588 % 8;
    int xcd = wg % 8, idx = wg / 8;
    bid = (xcd < r) ? xcd * (q + 1) + idx : r * (q + 1) + (xcd - r) * q + idx;
  }
  const int nb = bid % (E_ / 128);   // 0..5
  const int mb = bid / (E_ / 128);   // 0..97
  const int tid = threadIdx.x;
  const int w = tid >> 6, l = tid & 63;
  const int wr = w >> 1, wc = w & 1;

  __shared__ __align__(16) unsigned short As[128 * 32];
  __shared__ __align__(16) unsigned short Bs[128 * 32];

  f32x4 acc[4][4] = {};

  const int lrow = l >> 2;        // 0..15
  const int lcol = (l & 3) * 8;   // element offset within 32-wide K slice
  const int kk = (l >> 4) * 8;    // fragment K offset

  for (int k0 = 0; k0 < KP2_; k0 += 32) {
    #pragma unroll
    for (int q = 0; q < 2; ++q) {
      int r = (w * 2 + q) * 16 + lrow;
      const unsigned short* ga = A + (size_t)(mb * 128 + r) * KP2_ + k0 + lcol;
      __builtin_amdgcn_global_load_lds((const __attribute__((address_space(1))) unsigned int*)ga,
                                       (__attribute__((address_space(3))) unsigned int*)&As[(w * 2 + q) * 512],
                                       16, 0, 0);
      const unsigned short* gb = Bw + (size_t)(nb * 128 + r) * KP2_ + k0 + lcol;
      __builtin_amdgcn_global_load_lds((const __attribute__((address_space(1))) unsigned int*)gb,
                                       (__attribute__((address_space(3))) unsigned int*)&Bs[(w * 2 + q) * 512],
                                       16, 0, 0);
    }
    __syncthreads();

    short8 af[4], bf[4];
    #pragma unroll
    for (int mi = 0; mi < 4; ++mi)
      af[mi] = *(const short8*)&As[(wr * 64 + mi * 16 + (l & 15)) * 32 + kk];
    #pragma unroll
    for (int ni = 0; ni < 4; ++ni)
      bf[ni] = *(const short8*)&Bs[(wc * 64 + ni * 16 + (l & 15)) * 32 + kk];
    #pragma unroll
    for (int mi = 0; mi < 4; ++mi)
      #pragma unroll
      for (int ni = 0; ni < 4; ++ni)
        acc[mi][ni] = __builtin_amdgcn_mfma_f32_16x16x32_bf16(af[mi], bf[ni], acc[mi][ni], 0, 0, 0);
    __syncthreads();
  }

  // epilogue: C/D layout col = lane&15, row = (lane>>4)*4 + reg  [verified m89/m91]
  const int r0 = (l >> 4) * 4;
  const int c0 = l & 15;
  #pragma unroll
  for (int mi = 0; mi < 4; ++mi) {
    #pragma unroll
    for (int ni = 0; ni < 4; ++ni) {
      int col = nb * 128 + wc * 64 + ni * 16 + c0;
      float bv = bias[col];
      int row = mb * 128 + wr * 64 + mi * 16 + r0;
      #pragma unroll
      for (int r = 0; r < 4; ++r)
        out[(size_t)(row + r) * E_ + col] = acc[mi][ni][r] + bv;
    }
  }
}

extern "C" void kernel_launch(void* const* d_in, const int* in_sizes, int n_in,
                              void* d_out, int out_size, void* d_ws, size_t ws_size,
                              hipStream_t stream) {
  const float* img  = (const float*)d_in[0];   // [64,3,224,224]
  const int*   seg  = (const int*)d_in[1];     // [64,224,224]
  const float* Wf   = (const float*)d_in[2];   // [768,1200]
  const float* bias = (const float*)d_in[3];   // [768]
  float* out = (float*)d_out;                  // [64,196,768] = 38.5 MB

  // d_ws (42.6 MB <= proven 43.7): [Wb 2.46M][feats 40.14M]
  // d_out doubles as scratch for rloc/hist/cnts (11.4 MB), all dead before
  // gemm_k overwrites every element of d_out.
  constexpr size_t WB_BYTES    = (size_t)E_ * KP2_ * 2;       //  2,457,600
  constexpr size_t RLOC_BYTES  = (size_t)B_ * P_ * 2;         //  6,422,528
  constexpr size_t HIST_BYTES  = (size_t)B_ * NCH_ * S_ * 4;  //  4,917,248
  char* ws = (char*)d_ws;
  unsigned short* Wb    = (unsigned short*)ws;
  unsigned short* feats = (unsigned short*)(ws + WB_BYTES);
  char* oscr = (char*)d_out;
  unsigned short* rloc  = (unsigned short*)oscr;
  int*            hist  = (int*)(oscr + RLOC_BYTES);
  int*            cnts  = (int*)(oscr + RLOC_BYTES + HIST_BYTES);

  prep_k<<<RANK_BLOCKS + WCONV_BLOCKS, 512, 0, stream>>>(Wf, Wb, seg, hist, rloc);
  prefix_k<<<PREFIX_BLOCKS, 128, 0, stream>>>(hist, cnts);
  scatter_tail_k<<<SCAT_BLOCKS + TAIL_BLOCKS, 256, 0, stream>>>(img, seg, hist, rloc, cnts, feats);
  gemm_k<<<(M_ / 128) * (E_ / 128), 256, 0, stream>>>(feats, Wb, bias, out);
}